// Round 1
// baseline (582.379 us; speedup 1.0000x reference)
//
#include <hip/hip_runtime.h>
#include <math.h>

// Problem constants (fixed by reference)
#define NXg 48
#define NYg 48
#define Tg 512
#define Bg 4
#define NEg 5000
#define NG (Bg * NEg)          // 20000 electrons total (b folded in)
#define H1g 64
#define H2g 128

// Tiling
#define TT 32                  // ticks per bin/tile
#define NBINS (Tg / TT)        // 16
#define CAP 4096               // per-bin electron list capacity (avg ~2656)
#define SPLIT 4                // split-K over each bin's list
#define ECH 64                 // electrons staged per chunk

// ws layout: edata float4[NG] | cnt int[NBINS] | list int[NBINS*CAP]
// total: 320000 + 64 + 262144 bytes ≈ 582 KB

// ---------------------------------------------------------------------------
// Kernel 1: per-electron MLP + amplitude fold + time-bin list build
// amp = resp * mask * (100/(es*2.5066)) * (GAUSS_NORM/sqrt(5))
// ---------------------------------------------------------------------------
__global__ __launch_bounds__(256) void k_electron(
    const float* __restrict__ sim,    // (B,NE,2)
    const float* __restrict__ zpos,   // (B,NE)
    const float* __restrict__ mask,   // (B,NE)
    const float* __restrict__ W1, const float* __restrict__ b1,
    const float* __restrict__ W2, const float* __restrict__ b2,
    const float* __restrict__ W3, const float* __restrict__ b3,
    const float* __restrict__ el_spread,
    float4* __restrict__ edata,
    int* __restrict__ cnt, int* __restrict__ list)
{
    int g = blockIdx.x * blockDim.x + threadIdx.x;
    if (g >= NG) return;

    float x0 = sim[2 * g], x1 = sim[2 * g + 1];

    // layer 1: 2 -> 64
    float h1[H1g];
#pragma unroll
    for (int j = 0; j < H1g; ++j)
        h1[j] = fmaxf(fmaf(x0, W1[j], fmaf(x1, W1[H1g + j], b1[j])), 0.0f);

    // layer 2+3 fused: resp = b3 + sum_k relu(b2[k] + h1·W2[:,k]) * W3[k]
    float resp = b3[0];
    for (int k = 0; k < H2g; k += 2) {
        float a0 = b2[k], a1 = b2[k + 1];
#pragma unroll
        for (int j = 0; j < H1g; ++j) {
            float h = h1[j];
            a0 = fmaf(h, W2[j * H2g + k], a0);
            a1 = fmaf(h, W2[j * H2g + k + 1], a1);
        }
        resp = fmaf(fmaxf(a0, 0.0f), W3[k], resp);
        resp = fmaf(fmaxf(a1, 0.0f), W3[k + 1], resp);
    }

    float es = el_spread[0];
    float z = zpos[g];
    // 100/(es*EL_NORM) spatial norm, GAUSS_NORM/sqrt(BIN_SIGMA) time norm, mask
    float amp = resp * mask[g] * (100.0f / (es * 2.5066f)) *
                (0.3989422804f / 2.23606797749979f);
    edata[g] = make_float4(x0, x1, z, amp);

    // bins j with ticks [32j, 32j+31]; keep if min |t-z| <= 17.5
    // (dropped terms < exp(-17.5^2/10) = exp(-30.6) ~ 5e-14 of peak)
    int jlo = (int)ceilf((z - 48.5f) * (1.0f / TT));
    int jhi = (int)floorf((z + 17.5f) * (1.0f / TT));
    if (jlo < 0) jlo = 0;
    if (jhi > NBINS - 1) jhi = NBINS - 1;
    for (int j = jlo; j <= jhi; ++j) {
        int p = atomicAdd(&cnt[j], 1);
        if (p < CAP) list[j * CAP + p] = g;
    }
}

// ---------------------------------------------------------------------------
// Kernel 2: main accumulation.
// Grid: (9 spatial tiles of 16x16, 16 t-bins, SPLIT). Block: 256 threads,
// 1 sensor cell per thread, acc over 32 ticks in registers (8 x float4).
// Per staged electron: 1 exp for spatial weight, 32 FMAs vs LDS time profile
// (amp pre-folded). LDS reads are wave-uniform -> broadcast, conflict-free.
// ---------------------------------------------------------------------------
__global__ __launch_bounds__(256) void k_main(
    const float4* __restrict__ edata,
    const int* __restrict__ cnt, const int* __restrict__ list,
    const float* __restrict__ el_spread,
    const float* __restrict__ sensors,   // (48,48,2)
    float* __restrict__ out)             // (48,48,512), pre-zeroed
{
    __shared__ float4 se[ECH];
    __shared__ float4 sft4[ECH * TT / 4];   // time profiles, amp folded

    int tid = threadIdx.x;
    int tileId = blockIdx.x;       // 0..8
    int bin = blockIdx.y;          // 0..15
    int split = blockIdx.z;        // 0..SPLIT-1

    int sx0 = (tileId % 3) * 16;
    int sy0 = (tileId / 3) * 16;
    int lx = tid & 15, ly = tid >> 4;
    int x = sx0 + lx, y = sy0 + ly;
    float sx = sensors[(x * NYg + y) * 2 + 0];
    float sy = sensors[(x * NYg + y) * 2 + 1];
    float es = el_spread[0];
    float inv2 = -0.5f / (es * es);
    int t0 = bin * TT;

    int count = cnt[bin];
    if (count > CAP) count = CAP;
    int start = (count * split) / SPLIT;
    int end = (count * (split + 1)) / SPLIT;

    float4 acc[8];
#pragma unroll
    for (int q = 0; q < 8; ++q) acc[q] = make_float4(0.f, 0.f, 0.f, 0.f);

    for (int base = start; base < end; base += ECH) {
        int n = min(ECH, end - base);
        __syncthreads();   // previous chunk's reads done before overwrite
        if (tid < n) {
            int idx = list[bin * CAP + base + tid];
            se[tid] = edata[idx];
        }
        __syncthreads();
        {
            // 2048 time-profile values: 4 threads per electron, 8 ticks each
            int e = tid >> 2;
            int tl = (tid & 3) * 8;
            if (e < n) {
                float z = se[e].z, amp = se[e].w;
                float tbase = (float)(t0 + tl) - z;
                float v[8];
#pragma unroll
                for (int q = 0; q < 8; ++q) {
                    float d = tbase + (float)q;
                    v[q] = amp * __expf(-0.1f * d * d);
                }
                sft4[(e * TT + tl) / 4 + 0] = make_float4(v[0], v[1], v[2], v[3]);
                sft4[(e * TT + tl) / 4 + 1] = make_float4(v[4], v[5], v[6], v[7]);
            }
        }
        __syncthreads();
        for (int i = 0; i < n; ++i) {
            float4 E = se[i];
            float dx = sx - E.x, dy = sy - E.y;
            float expo = inv2 * fmaf(dx, dx, dy * dy);
            bool act = expo > -30.0f;   // exp(-30) ~ 9e-14 of peak: negligible
            if (__any(act)) {
                float c = act ? __expf(expo) : 0.0f;
                const float4* f4 = &sft4[i * (TT / 4)];
#pragma unroll
                for (int q = 0; q < 8; ++q) {
                    float4 f = f4[q];
                    acc[q].x = fmaf(c, f.x, acc[q].x);
                    acc[q].y = fmaf(c, f.y, acc[q].y);
                    acc[q].z = fmaf(c, f.z, acc[q].z);
                    acc[q].w = fmaf(c, f.w, acc[q].w);
                }
            }
        }
    }

    float* op = out + ((size_t)(x * NYg + y)) * Tg + t0;
#pragma unroll
    for (int q = 0; q < 8; ++q) {
        atomicAdd(&op[4 * q + 0], acc[q].x);
        atomicAdd(&op[4 * q + 1], acc[q].y);
        atomicAdd(&op[4 * q + 2], acc[q].z);
        atomicAdd(&op[4 * q + 3], acc[q].w);
    }
}

// ---------------------------------------------------------------------------
extern "C" void kernel_launch(void* const* d_in, const int* in_sizes, int n_in,
                              void* d_out, int out_size, void* d_ws, size_t ws_size,
                              hipStream_t stream)
{
    const float* sim       = (const float*)d_in[0];
    const float* zpos      = (const float*)d_in[1];
    const float* mask      = (const float*)d_in[2];
    const float* W1        = (const float*)d_in[3];
    const float* b1        = (const float*)d_in[4];
    const float* W2        = (const float*)d_in[5];
    const float* b2        = (const float*)d_in[6];
    const float* W3        = (const float*)d_in[7];
    const float* b3        = (const float*)d_in[8];
    const float* el_spread = (const float*)d_in[9];
    const float* sensors   = (const float*)d_in[10];
    float* out = (float*)d_out;

    float4* edata = (float4*)d_ws;
    int* cnt  = (int*)((char*)d_ws + (size_t)NG * sizeof(float4));
    int* list = cnt + NBINS;

    hipMemsetAsync(d_out, 0, (size_t)out_size * sizeof(float), stream);
    hipMemsetAsync(cnt, 0, NBINS * sizeof(int), stream);

    k_electron<<<(NG + 255) / 256, 256, 0, stream>>>(
        sim, zpos, mask, W1, b1, W2, b2, W3, b3, el_spread, edata, cnt, list);

    k_main<<<dim3(9, NBINS, SPLIT), 256, 0, stream>>>(
        edata, cnt, list, el_spread, sensors, out);
}

// Round 2
// 356.918 us; speedup vs baseline: 1.6317x; 1.6317x over previous
//
#include <hip/hip_runtime.h>
#include <math.h>

// Problem constants (fixed by reference)
#define NXg 48
#define NYg 48
#define Tg 512
#define Bg 4
#define NEg 5000
#define NG (Bg * NEg)          // 20000 electrons (batch folded in)
#define H1g 64
#define H2g 128

// Tiling
#define TT 32                  // ticks per time bin
#define NBINS (Tg / TT)        // 16
#define CAP 4096               // per-bin electron list capacity (avg ~2650)
#define SPLIT 8                // split-K over each bin's list
#define KSPLIT 8               // k_electron H2 split

// ---------------------------------------------------------------------------
// ws layout (all float4 arrays 16B aligned):
//   prof : float[(NBINS*CAP+1)*TT]                  8,388,736 B  (amp-folded time profiles)
//   part : float[SPLIT*9*NBINS*8192]               37,748,736 B  (split-K partials)
//   edata: float4[NG]                                 320,000 B  (x,y,z,mask)
//   pos2 : float2[NBINS*CAP+1]                        524,304 B  (padded)
//   resp : float[NG]                                   80,000 B
//   list : int[NBINS*CAP]                             262,144 B
//   cnt  : int[NBINS]                                      64 B
// total ~47.3 MB
// ---------------------------------------------------------------------------
#define OFF_PROF  0
#define OFF_PART  (OFF_PROF + (size_t)(NBINS*CAP + 1) * TT * 4)
#define OFF_EDATA (OFF_PART + (size_t)SPLIT * 9 * NBINS * 8192 * 4)
#define OFF_POS2  (OFF_EDATA + (size_t)NG * 16)
#define OFF_RESP  (OFF_POS2 + (size_t)(NBINS*CAP + 1) * 8 + 8)
#define OFF_LIST  (OFF_RESP + (size_t)NG * 4)
#define OFF_CNT   (OFF_LIST + (size_t)NBINS * CAP * 4)

// ---------------------------------------------------------------------------
// Kernel 1: per-electron MLP (H2 split 8-way for parallelism) + bin lists.
// ---------------------------------------------------------------------------
__global__ __launch_bounds__(256) void k_electron(
    const float* __restrict__ sim, const float* __restrict__ zpos,
    const float* __restrict__ mask,
    const float* __restrict__ W1, const float* __restrict__ b1,
    const float* __restrict__ W2, const float* __restrict__ b2,
    const float* __restrict__ W3, const float* __restrict__ b3,
    float4* __restrict__ edata, float* __restrict__ resp,
    int* __restrict__ cnt, int* __restrict__ list)
{
    int g = blockIdx.x * 256 + threadIdx.x;
    int q = blockIdx.y;                 // 0..KSPLIT-1, H2 chunk
    if (g >= NG) return;

    float x0 = sim[2 * g], x1 = sim[2 * g + 1];

    // layer 1: 2 -> 64 (recomputed per q; trivial)
    float h1[H1g];
#pragma unroll
    for (int j = 0; j < H1g; ++j)
        h1[j] = fmaxf(fmaf(x0, W1[j], fmaf(x1, W1[H1g + j], b1[j])), 0.0f);

    // partial of layers 2+3 over k in [k0, k0+16)
    int k0 = q * (H2g / KSPLIT);
    float r = 0.0f;
    for (int k = k0; k < k0 + H2g / KSPLIT; k += 2) {
        float a0 = b2[k], a1 = b2[k + 1];
#pragma unroll
        for (int j = 0; j < H1g; ++j) {
            float h = h1[j];
            a0 = fmaf(h, W2[j * H2g + k], a0);
            a1 = fmaf(h, W2[j * H2g + k + 1], a1);
        }
        r = fmaf(fmaxf(a0, 0.0f), W3[k], r);
        r = fmaf(fmaxf(a1, 0.0f), W3[k + 1], r);
    }
    if (q == 0) r += b3[0];
    atomicAdd(&resp[g], r);

    if (q == 0) {
        float z = zpos[g];
        edata[g] = make_float4(x0, x1, z, mask[g]);
        // bins overlapping |t - z| <= 17.5 (dropped terms < 5e-14 of peak)
        int jlo = (int)ceilf((z - 48.5f) * (1.0f / TT));
        int jhi = (int)floorf((z + 17.5f) * (1.0f / TT));
        jlo = max(jlo, 0);
        jhi = min(jhi, NBINS - 1);
        for (int j = jlo; j <= jhi; ++j) {
            int p = atomicAdd(&cnt[j], 1);
            if (p < CAP) list[j * CAP + p] = g;
        }
    }
}

// ---------------------------------------------------------------------------
// Kernel 2: amp-folded time profiles -> prof[], positions -> pos2[].
// 4 threads per list entry, 8 ticks each.
// ---------------------------------------------------------------------------
__global__ __launch_bounds__(256) void k_prof(
    const float4* __restrict__ edata, const float* __restrict__ resp,
    const int* __restrict__ cnt, const int* __restrict__ list,
    const float* __restrict__ el_spread,
    float* __restrict__ prof, float2* __restrict__ pos2)
{
    int bin = blockIdx.y;
    int i = blockIdx.x * 64 + (threadIdx.x >> 2);
    int tl = (threadIdx.x & 3) * 8;
    int count = min(cnt[bin], CAP);
    if (i >= count) return;

    int g = list[bin * CAP + i];
    float4 E = edata[g];
    float es = el_spread[0];
    // fold: resp * mask * 100/(es*EL_NORM) * GAUSS_NORM/sqrt(BIN_SIGMA)
    float amp = resp[g] * E.w * (100.0f / (es * 2.5066f)) *
                (0.3989422804f / 2.23606797749979f);
    float tb = (float)(bin * TT + tl) - E.z;
    float v[8];
#pragma unroll
    for (int u = 0; u < 8; ++u) {
        float d = tb + (float)u;
        v[u] = amp * __expf(-0.1f * d * d);
    }
    float4* P = (float4*)&prof[((size_t)bin * CAP + i) * TT + tl];
    P[0] = make_float4(v[0], v[1], v[2], v[3]);
    P[1] = make_float4(v[4], v[5], v[6], v[7]);
    if (tl == 0) pos2[bin * CAP + i] = make_float2(E.x, E.y);
}

// ---------------------------------------------------------------------------
// Kernel 3: main rank-1 accumulation. Per-electron data (profile f[32],
// position) is WAVE-UNIFORM -> loads lower to s_load (scalar pipe), zero LDS.
// Thread = 1 sensor, 32-tick register accumulator. Software-pipelined depth 1.
// Output: split-K partials, coalesced float4 stores (no atomics).
// ---------------------------------------------------------------------------
__global__ __launch_bounds__(256) void k_main(
    const float* __restrict__ prof, const float2* __restrict__ pos2,
    const int* __restrict__ cnt,
    const float* __restrict__ el_spread, const float* __restrict__ sensors,
    float4* __restrict__ part)
{
    int tid = threadIdx.x;
    int tile = blockIdx.x;         // 0..8 (3x3 of 16x16 sensor tiles)
    int bin = blockIdx.y;          // 0..15
    int split = blockIdx.z;        // 0..SPLIT-1

    int lx = tid & 15, ly = tid >> 4;
    int x = (tile % 3) * 16 + lx;
    int y = (tile / 3) * 16 + ly;
    float sx = sensors[(x * NYg + y) * 2 + 0];
    float sy = sensors[(x * NYg + y) * 2 + 1];
    float es = el_spread[0];
    float inv2 = -0.5f / (es * es);

    int count = min(cnt[bin], CAP);
    int start = count * split / SPLIT;
    int end = count * (split + 1) / SPLIT;

    float acc[TT];
#pragma unroll
    for (int t = 0; t < TT; ++t) acc[t] = 0.0f;

    const float4* pb = (const float4*)(prof + (size_t)bin * CAP * TT);
    const float2* qb = pos2 + bin * CAP;

    if (start < end) {
        float4 f[8];
        float2 P;
#pragma unroll
        for (int u = 0; u < 8; ++u) f[u] = pb[start * 8 + u];
        P = qb[start];

        for (int i = start; i < end; ++i) {
            // prefetch next entry (over-read at i+1==CAP is padded & unused)
            float4 g4[8];
            float2 Q;
#pragma unroll
            for (int u = 0; u < 8; ++u) g4[u] = pb[(i + 1) * 8 + u];
            Q = qb[i + 1];

            float dx = sx - P.x, dy = sy - P.y;
            float expo = inv2 * fmaf(dx, dx, dy * dy);
            if (__any(expo > -30.0f)) {          // exp(-30) ~ 9e-14 of peak
                float c = expo > -30.0f ? __expf(expo) : 0.0f;
#pragma unroll
                for (int u = 0; u < 8; ++u) {
                    acc[4 * u + 0] = fmaf(c, f[u].x, acc[4 * u + 0]);
                    acc[4 * u + 1] = fmaf(c, f[u].y, acc[4 * u + 1]);
                    acc[4 * u + 2] = fmaf(c, f[u].z, acc[4 * u + 2]);
                    acc[4 * u + 3] = fmaf(c, f[u].w, acc[4 * u + 3]);
                }
            }
#pragma unroll
            for (int u = 0; u < 8; ++u) f[u] = g4[u];
            P = Q;
        }
    }

    // coalesced partial store: lane-consecutive float4s
    float4* pp = part + ((((size_t)split * 9 + tile) * NBINS + bin) * 2048);
#pragma unroll
    for (int u = 0; u < 8; ++u)
        pp[u * 256 + tid] =
            make_float4(acc[4 * u], acc[4 * u + 1], acc[4 * u + 2], acc[4 * u + 3]);
}

// ---------------------------------------------------------------------------
// Kernel 4: reduce split-K partials into the output (writes every element,
// so no d_out memset needed).
// ---------------------------------------------------------------------------
__global__ __launch_bounds__(256) void k_reduce(
    const float4* __restrict__ part, float* __restrict__ out)
{
    int tile = blockIdx.x, bin = blockIdx.y, tid = threadIdx.x;
    int lx = tid & 15, ly = tid >> 4;
    int x = (tile % 3) * 16 + lx;
    int y = (tile / 3) * 16 + ly;
    float* op = out + ((size_t)(x * NYg + y)) * Tg + bin * TT;

#pragma unroll
    for (int u = 0; u < 8; ++u) {
        float4 s = make_float4(0.f, 0.f, 0.f, 0.f);
        for (int sp = 0; sp < SPLIT; ++sp) {
            float4 v = part[(((size_t)sp * 9 + tile) * NBINS + bin) * 2048 +
                            u * 256 + tid];
            s.x += v.x; s.y += v.y; s.z += v.z; s.w += v.w;
        }
        *(float4*)(op + u * 4) = s;
    }
}

// ---------------------------------------------------------------------------
extern "C" void kernel_launch(void* const* d_in, const int* in_sizes, int n_in,
                              void* d_out, int out_size, void* d_ws, size_t ws_size,
                              hipStream_t stream)
{
    const float* sim       = (const float*)d_in[0];
    const float* zpos      = (const float*)d_in[1];
    const float* mask      = (const float*)d_in[2];
    const float* W1        = (const float*)d_in[3];
    const float* b1        = (const float*)d_in[4];
    const float* W2        = (const float*)d_in[5];
    const float* b2        = (const float*)d_in[6];
    const float* W3        = (const float*)d_in[7];
    const float* b3        = (const float*)d_in[8];
    const float* el_spread = (const float*)d_in[9];
    const float* sensors   = (const float*)d_in[10];
    float* out = (float*)d_out;

    char* ws = (char*)d_ws;
    float*  prof  = (float*)(ws + OFF_PROF);
    float4* part  = (float4*)(ws + OFF_PART);
    float4* edata = (float4*)(ws + OFF_EDATA);
    float2* pos2  = (float2*)(ws + OFF_POS2);
    float*  resp  = (float*)(ws + OFF_RESP);
    int*    list  = (int*)(ws + OFF_LIST);
    int*    cnt   = (int*)(ws + OFF_CNT);

    hipMemsetAsync(resp, 0, (size_t)NG * 4, stream);
    hipMemsetAsync(cnt, 0, NBINS * sizeof(int), stream);

    k_electron<<<dim3((NG + 255) / 256, KSPLIT), 256, 0, stream>>>(
        sim, zpos, mask, W1, b1, W2, b2, W3, b3, edata, resp, cnt, list);

    k_prof<<<dim3(CAP / 64, NBINS), 256, 0, stream>>>(
        edata, resp, cnt, list, el_spread, prof, pos2);

    k_main<<<dim3(9, NBINS, SPLIT), 256, 0, stream>>>(
        prof, pos2, cnt, el_spread, sensors, part);

    k_reduce<<<dim3(9, NBINS), 256, 0, stream>>>(part, out);
}